// Round 3
// baseline (136.780 us; speedup 1.0000x reference)
//
#include <hip/hip_runtime.h>
#include <math.h>

#define NQ 10
#define RPB 4          // rows per block
#define NTERMS 882

// ---------------------------------------------------------------------------
// Setup kernel: build the 882-term Pauli table + layer-0 Rot matrices from
// qweights. Heisenberg picture: Z_q -> (ring2 conj) Z-string -> (layer-1 Rot
// conj) {X,Y,Z}-strings -> (ring1 conj, symplectic) final Pauli string + sign.
// Term j: packed pair-nibbles (5 x 4 bits, code = x | z<<1 per site) + coef.
// ---------------------------------------------------------------------------
__global__ __launch_bounds__(1024) void qse_setup(const float* __restrict__ qw,
                                                  uint2* __restrict__ terms,
                                                  float* __restrict__ Rmat) {
    __shared__ float abc[NQ][3];
    const int t = threadIdx.x;
    if (t < NQ) {
        // ---- layer-0 Rot matrix -> Rmat (8 floats/qubit) ----
        {
            float phi = qw[t * 3 + 0], th = qw[t * 3 + 1], om = qw[t * 3 + 2];
            float st_, ct;  sincosf(0.5f * th, &st_, &ct);
            float spo, cpo; sincosf(0.5f * (phi + om), &spo, &cpo);
            float spm, cpm; sincosf(0.5f * (phi - om), &spm, &cpm);
            Rmat[t * 8 + 0] =  cpo * ct;  Rmat[t * 8 + 1] = -spo * ct;
            Rmat[t * 8 + 2] = -cpm * st_; Rmat[t * 8 + 3] = -spm * st_;
            Rmat[t * 8 + 4] =  cpm * st_; Rmat[t * 8 + 5] = -spm * st_;
            Rmat[t * 8 + 6] =  cpo * ct;  Rmat[t * 8 + 7] =  spo * ct;
        }
        // ---- layer-1 Rot: A = G† Z G Bloch coefficients ----
        {
            float phi = qw[30 + t * 3 + 0], th = qw[30 + t * 3 + 1], om = qw[30 + t * 3 + 2];
            float st_, ct;  sincosf(0.5f * th, &st_, &ct);
            float spo, cpo; sincosf(0.5f * (phi + om), &spo, &cpo);
            float spm, cpm; sincosf(0.5f * (phi - om), &spm, &cpm);
            float2 G00 = make_float2(cpo * ct, -spo * ct);
            float2 G01 = make_float2(-cpm * st_, -spm * st_);
            float2 G10 = make_float2(cpm * st_, -spm * st_);
            float2 G11 = make_float2(cpo * ct, spo * ct);
            float re = G00.x * G01.x + G00.y * G01.y - (G10.x * G11.x + G10.y * G11.y);
            float im = G00.x * G01.y - G00.y * G01.x - (G10.x * G11.y - G10.y * G11.x);
            float A00 = G00.x * G00.x + G00.y * G00.y - (G10.x * G10.x + G10.y * G10.y);
            float A11 = G01.x * G01.x + G01.y * G01.y - (G11.x * G11.x + G11.y * G11.y);
            abc[t][0] = re;
            abc[t][1] = -im;
            abc[t][2] = 0.5f * (A00 - A11);
        }
    }
    __syncthreads();
    if (t >= NTERMS) return;

    // locate q + Z-string S_q (ring-2 conjugation: pure toggles)
    int base = 0, smask = 0;
    for (int qq = 0; qq < NQ; ++qq) {
        int m = 1 << qq;
        for (int i = NQ - 1; i >= 0; --i) {
            int tt = (i + 2) % NQ;
            if ((m >> tt) & 1) m ^= 1 << i;
        }
        int L = __popc(m);
        int cnt = 1;
        for (int k = 0; k < L; ++k) cnt *= 3;
        if (t < base + cnt) { smask = m; break; }
        base += cnt;
    }
    int rem = t - base;

    unsigned xm = 0, zm = 0;
    float coef = 1.f;
    for (int i = 0; i < NQ; ++i) {
        if ((smask >> i) & 1) {
            int d = rem % 3; rem /= 3;
            coef *= abc[i][d];
            if (d == 0)      { xm |= 1u << i; }
            else if (d == 1) { xm |= 1u << i; zm |= 1u << i; }
            else             { zm |= 1u << i; }
        }
    }
    // ring-1 conjugation (CNOT(i,(i+1)%10), conjugate by i=9 first)
    unsigned s = 0;
    for (int i = NQ - 1; i >= 0; --i) {
        int c = i, tt = (i + 1) % NQ;
        unsigned xc = (xm >> c) & 1u, zt = (zm >> tt) & 1u;
        unsigned xt = (xm >> tt) & 1u, zc = (zm >> c) & 1u;
        s ^= xc & zt & (xt ^ zc ^ 1u);
        xm ^= xc << tt;
        zm ^= zt << c;
    }
    if (s) coef = -coef;

    unsigned nib = 0;
    for (int p = 0; p < 5; ++p) {
        unsigned c0 = ((xm >> (2 * p)) & 1u) | (((zm >> (2 * p)) & 1u) << 1);
        unsigned c1 = ((xm >> (2 * p + 1)) & 1u) | (((zm >> (2 * p + 1)) & 1u) << 1);
        nib |= (c0 | (c1 << 2)) << (4 * p);
    }
    terms[t] = make_uint2(nib, __float_as_uint(coef));
}

// ---------------------------------------------------------------------------
// Main kernel: 4 rows per block, 256 threads, 1024 blocks (all resident).
// ---------------------------------------------------------------------------
__global__ __launch_bounds__(256, 4) void qse_main(
    const float* __restrict__ x,     // (4096,512)
    const float* __restrict__ W_in,  // (512,10)
    const float* __restrict__ b_in,  // (10)
    const float* __restrict__ W1,    // (10,64)
    const float* __restrict__ b1,    // (64)
    const float* __restrict__ W2,    // (64,256)
    const float* __restrict__ b2,    // (256)
    const uint2* __restrict__ terms, // (882)
    const float* __restrict__ Rmat,  // (10,8)
    float* __restrict__ out)         // (4096,256)
{
    __shared__ float ang[RPB][NQ];
    __shared__ float E1[RPB][NQ][4];     // per-site {1, <X>, <Z>, <Y>} (code=x|z<<1)
    __shared__ float E2d[RPB][5][32];    // pair products, duplicated x2
    __shared__ float part[RPB][256];
    __shared__ float zsh[RPB][NQ];
    __shared__ float hsh[RPB][64];

    const int t = threadIdx.x;
    const int lane = t & 63;
    const int wv = t >> 6;               // wave id = row within block
    const int row0 = blockIdx.x * RPB;

    // ---- p1: wave wv computes angles for row row0+wv ----
    {
        float acc[NQ];
        #pragma unroll
        for (int q = 0; q < NQ; ++q) acc[q] = 0.f;
        const float* xr = x + (size_t)(row0 + wv) * 512;
        #pragma unroll
        for (int k = 0; k < 8; ++k) {
            int j = lane + 64 * k;
            float xv = xr[j];
            const float2* wr = (const float2*)(W_in + j * NQ);
            #pragma unroll
            for (int h = 0; h < 5; ++h) {
                float2 w2 = wr[h];
                acc[2 * h]     = fmaf(xv, w2.x, acc[2 * h]);
                acc[2 * h + 1] = fmaf(xv, w2.y, acc[2 * h + 1]);
            }
        }
        #pragma unroll
        for (int off = 32; off > 0; off >>= 1) {
            #pragma unroll
            for (int q = 0; q < NQ; ++q) acc[q] += __shfl_xor(acc[q], off);
        }
        if (lane == 0) {
            #pragma unroll
            for (int q = 0; q < NQ; ++q) ang[wv][q] = acc[q];
        }
    }
    __syncthreads();

    // ---- p2: per-(row,qubit) Bloch expectations of u = Rot0 * RX |0> ----
    if (t < RPB * NQ) {
        const int rr = t / NQ, i = t % NQ;
        float a = ang[rr][i] + b_in[i];
        float s, c; sincosf(0.5f * a, &s, &c);
        const float* Rp = Rmat + i * 8;
        float2 u0 = make_float2(fmaf(Rp[0], c, s * Rp[3]), fmaf(Rp[1], c, -s * Rp[2]));
        float2 u1 = make_float2(fmaf(Rp[4], c, s * Rp[7]), fmaf(Rp[5], c, -s * Rp[6]));
        float ex = 2.f * (u0.x * u1.x + u0.y * u1.y);
        float ey = 2.f * (u0.x * u1.y - u0.y * u1.x);
        float ez = u0.x * u0.x + u0.y * u0.y - u1.x * u1.x - u1.y * u1.y;
        E1[rr][i][0] = 1.f; E1[rr][i][1] = ex; E1[rr][i][2] = ez; E1[rr][i][3] = ey;
    }
    __syncthreads();

    // ---- pair products, duplicated for conflict-free reads ----
    if (t < 80) {
        const int rr = t / 20, rem = t % 20, p = rem / 4, c1 = rem % 4;
        const float e1 = E1[rr][2 * p + 1][c1];
        #pragma unroll
        for (int c0 = 0; c0 < 4; ++c0) {
            float v = E1[rr][2 * p][c0] * e1;
            int idx = c0 | (c1 << 2);
            E2d[rr][p][2 * idx]     = v;
            E2d[rr][p][2 * idx + 1] = v;
        }
    }
    __syncthreads();

    // ---- p3: contract 882 terms (threads partitioned by output q) ----
    {
        int l, nqt, off, cnt;
        if      (t < 24)  { l = t;       nqt = 24; off = 0;   cnt = 81;  }
        else if (t < 48)  { l = t - 24;  nqt = 24; off = 81;  cnt = 81;  }
        else if (t < 51)  { l = t - 48;  nqt = 3;  off = 162; cnt = 9;   }
        else if (t < 54)  { l = t - 51;  nqt = 3;  off = 171; cnt = 9;   }
        else if (t < 62)  { l = t - 54;  nqt = 8;  off = 180; cnt = 27;  }
        else if (t < 70)  { l = t - 62;  nqt = 8;  off = 207; cnt = 27;  }
        else if (t < 94)  { l = t - 70;  nqt = 24; off = 234; cnt = 81;  }
        else if (t < 118) { l = t - 94;  nqt = 24; off = 315; cnt = 81;  }
        else if (t < 187) { l = t - 118; nqt = 69; off = 396; cnt = 243; }
        else              { l = t - 187; nqt = 69; off = 639; cnt = 243; }

        const int par = t & 1;
        float accR[RPB];
        #pragma unroll
        for (int rr = 0; rr < RPB; ++rr) accR[rr] = 0.f;

        #pragma unroll
        for (int jj = 0; jj < 4; ++jj) {
            int j = off + l + jj * nqt;
            uint2 tm = make_uint2(0u, 0u);
            if (j < off + cnt) tm = terms[j];
            const float coef = __uint_as_float(tm.y);
            const unsigned nib = tm.x;
            #pragma unroll
            for (int rr = 0; rr < RPB; ++rr) {
                float pr = coef;
                #pragma unroll
                for (int p = 0; p < 5; ++p)
                    pr *= E2d[rr][p][2 * ((nib >> (4 * p)) & 15u) + par];
                accR[rr] += pr;
            }
        }
        #pragma unroll
        for (int rr = 0; rr < RPB; ++rr) part[rr][t] = accR[rr];
    }
    __syncthreads();

    // ---- group reduction: 40 threads, one per (row, q) ----
    if (t < RPB * NQ) {
        const int rr = t / NQ, q = t % NQ;
        int lo, hi;
        if      (q == 0) { lo = 0;   hi = 24;  }
        else if (q == 1) { lo = 24;  hi = 48;  }
        else if (q == 2) { lo = 48;  hi = 51;  }
        else if (q == 3) { lo = 51;  hi = 54;  }
        else if (q == 4) { lo = 54;  hi = 62;  }
        else if (q == 5) { lo = 62;  hi = 70;  }
        else if (q == 6) { lo = 70;  hi = 94;  }
        else if (q == 7) { lo = 94;  hi = 118; }
        else if (q == 8) { lo = 118; hi = 187; }
        else             { lo = 187; hi = 256; }
        float s = 0.f;
        for (int j = lo; j < hi; ++j) s += part[rr][j];
        zsh[rr][q] = s;
    }
    __syncthreads();

    // ---- p4: h = relu(z @ W1 + b1); 4 rows x 64 cols = 256 threads ----
    {
        const int rr = t >> 6, c = t & 63;
        float a = b1[c];
        #pragma unroll
        for (int i = 0; i < NQ; ++i) a = fmaf(zsh[rr][i], W1[i * 64 + c], a);
        hsh[rr][c] = fmaxf(a, 0.f);
    }
    __syncthreads();

    // ---- p5: out = tanh(h @ W2 + b2), thread owns column t for 4 rows ----
    {
        float oacc[RPB];
        #pragma unroll
        for (int rr = 0; rr < RPB; ++rr) oacc[rr] = b2[t];
        for (int j4 = 0; j4 < 16; ++j4) {
            float4 hv[RPB];
            #pragma unroll
            for (int rr = 0; rr < RPB; ++rr) hv[rr] = *(const float4*)&hsh[rr][4 * j4];
            const float w0 = W2[(4 * j4 + 0) * 256 + t];
            const float w1 = W2[(4 * j4 + 1) * 256 + t];
            const float w2 = W2[(4 * j4 + 2) * 256 + t];
            const float w3 = W2[(4 * j4 + 3) * 256 + t];
            #pragma unroll
            for (int rr = 0; rr < RPB; ++rr) {
                oacc[rr] = fmaf(hv[rr].x, w0, oacc[rr]);
                oacc[rr] = fmaf(hv[rr].y, w1, oacc[rr]);
                oacc[rr] = fmaf(hv[rr].z, w2, oacc[rr]);
                oacc[rr] = fmaf(hv[rr].w, w3, oacc[rr]);
            }
        }
        #pragma unroll
        for (int rr = 0; rr < RPB; ++rr)
            out[(size_t)(row0 + rr) * 256 + t] = tanhf(oacc[rr]);
    }
}

extern "C" void kernel_launch(void* const* d_in, const int* in_sizes, int n_in,
                              void* d_out, int out_size, void* d_ws, size_t ws_size,
                              hipStream_t stream) {
    const float* x    = (const float*)d_in[0];
    const float* W_in = (const float*)d_in[1];
    const float* b_in = (const float*)d_in[2];
    const float* qw   = (const float*)d_in[3];
    const float* W1   = (const float*)d_in[4];
    const float* b1   = (const float*)d_in[5];
    const float* W2   = (const float*)d_in[6];
    const float* b2   = (const float*)d_in[7];
    float* out = (float*)d_out;

    uint2* terms = (uint2*)d_ws;                       // 882*8 = 7056 B
    float* Rmat  = (float*)((char*)d_ws + 7168);       // 80 floats

    qse_setup<<<1, 1024, 0, stream>>>(qw, terms, Rmat);
    qse_main<<<4096 / RPB, 256, 0, stream>>>(x, W_in, b_in, W1, b1, W2, b2,
                                             (const uint2*)terms, (const float*)Rmat, out);
}

// Round 4
// 113.974 us; speedup vs baseline: 1.2001x; 1.2001x over previous
//
#include <hip/hip_runtime.h>
#include <math.h>

#define NQ 10
#define RPB 4            // rows per block
#define NPAD 1024        // padded term table (4*nqt per qubit)

// ---------------------------------------------------------------------------
// Setup kernel: build the PADDED 1024-slot Pauli term table + layer-0 Rot
// matrices from qweights. Heisenberg picture: Z_q -> (ring2 conj) Z-string ->
// (layer-1 Rot conj) {X,Y,Z}-strings -> (ring1 conj, symplectic) final Pauli
// string + sign. Slot layout: per qubit q a region of 4*nqt[q] slots starting
// at pbase[q]; valid terms [0,cnt) of that region, rest coef=0.
// Term: packed pair-nibbles (5 x 4 bits, code = x | z<<1 per site) + coef.
// ---------------------------------------------------------------------------
__global__ __launch_bounds__(1024) void qse_setup(const float* __restrict__ qw,
                                                  uint2* __restrict__ terms,
                                                  float* __restrict__ Rmat) {
    __shared__ float abc[NQ][3];
    const int t = threadIdx.x;
    if (t < NQ) {
        // ---- layer-0 Rot matrix -> Rmat (8 floats/qubit) ----
        {
            float phi = qw[t * 3 + 0], th = qw[t * 3 + 1], om = qw[t * 3 + 2];
            float st_, ct;  sincosf(0.5f * th, &st_, &ct);
            float spo, cpo; sincosf(0.5f * (phi + om), &spo, &cpo);
            float spm, cpm; sincosf(0.5f * (phi - om), &spm, &cpm);
            Rmat[t * 8 + 0] =  cpo * ct;  Rmat[t * 8 + 1] = -spo * ct;
            Rmat[t * 8 + 2] = -cpm * st_; Rmat[t * 8 + 3] = -spm * st_;
            Rmat[t * 8 + 4] =  cpm * st_; Rmat[t * 8 + 5] = -spm * st_;
            Rmat[t * 8 + 6] =  cpo * ct;  Rmat[t * 8 + 7] =  spo * ct;
        }
        // ---- layer-1 Rot: A = G† Z G Bloch coefficients ----
        {
            float phi = qw[30 + t * 3 + 0], th = qw[30 + t * 3 + 1], om = qw[30 + t * 3 + 2];
            float st_, ct;  sincosf(0.5f * th, &st_, &ct);
            float spo, cpo; sincosf(0.5f * (phi + om), &spo, &cpo);
            float spm, cpm; sincosf(0.5f * (phi - om), &spm, &cpm);
            float2 G00 = make_float2(cpo * ct, -spo * ct);
            float2 G01 = make_float2(-cpm * st_, -spm * st_);
            float2 G10 = make_float2(cpm * st_, -spm * st_);
            float2 G11 = make_float2(cpo * ct, spo * ct);
            float re = G00.x * G01.x + G00.y * G01.y - (G10.x * G11.x + G10.y * G11.y);
            float im = G00.x * G01.y - G00.y * G01.x - (G10.x * G11.y - G10.y * G11.x);
            float A00 = G00.x * G00.x + G00.y * G00.y - (G10.x * G10.x + G10.y * G10.y);
            float A11 = G01.x * G01.x + G01.y * G01.y - (G11.x * G11.x + G11.y * G11.y);
            abc[t][0] = re;
            abc[t][1] = -im;
            abc[t][2] = 0.5f * (A00 - A11);
        }
    }
    __syncthreads();

    // thread t owns padded slot t: find its qubit region
    const int nqt[NQ] = {24, 24, 3, 3, 8, 8, 24, 24, 69, 69};
    int base = 0, q = 0, idx = 0, smask = 0, cnt = 0;
    for (int qq = 0; qq < NQ; ++qq) {
        int m = 1 << qq;
        for (int ii = NQ - 1; ii >= 0; --ii) {
            int tt = (ii + 2) % NQ;
            if ((m >> tt) & 1) m ^= 1 << ii;
        }
        int L = __popc(m);
        int c = 1;
        for (int k = 0; k < L; ++k) c *= 3;
        int sz = 4 * nqt[qq];
        if (t < base + sz) { q = qq; idx = t - base; smask = m; cnt = c; break; }
        base += sz;
    }
    (void)q;
    if (idx >= cnt) { terms[t] = make_uint2(0u, 0u); return; }

    // expand: digit 0->X, 1->Y, 2->Z on each site of the Z-string
    int rem = idx;
    unsigned xm = 0, zm = 0;
    float coef = 1.f;
    for (int i = 0; i < NQ; ++i) {
        if ((smask >> i) & 1) {
            int d = rem % 3; rem /= 3;
            coef *= abc[i][d];
            if (d == 0)      { xm |= 1u << i; }
            else if (d == 1) { xm |= 1u << i; zm |= 1u << i; }
            else             { zm |= 1u << i; }
        }
    }
    // ring-1 conjugation (CNOT(i,(i+1)%10), conjugate by i=9 first)
    unsigned s = 0;
    for (int i = NQ - 1; i >= 0; --i) {
        int c = i, tt = (i + 1) % NQ;
        unsigned xc = (xm >> c) & 1u, zt = (zm >> tt) & 1u;
        unsigned xt = (xm >> tt) & 1u, zc = (zm >> c) & 1u;
        s ^= xc & zt & (xt ^ zc ^ 1u);
        xm ^= xc << tt;
        zm ^= zt << c;
    }
    if (s) coef = -coef;

    unsigned nib = 0;
    for (int p = 0; p < 5; ++p) {
        unsigned c0 = ((xm >> (2 * p)) & 1u) | (((zm >> (2 * p)) & 1u) << 1);
        unsigned c1 = ((xm >> (2 * p + 1)) & 1u) | (((zm >> (2 * p + 1)) & 1u) << 1);
        nib |= (c0 | (c1 << 2)) << (4 * p);
    }
    terms[t] = make_uint2(nib, __float_as_uint(coef));
}

// ---------------------------------------------------------------------------
// Main kernel: 4 rows per block, 256 threads, 1024 blocks.
// No launch-bounds min-waves: round 3 showed (256,4) clamps VGPR to 64 and
// spills ~200 MB of scratch to HBM. Let the compiler allocate freely.
// ---------------------------------------------------------------------------
__global__ __launch_bounds__(256) void qse_main(
    const float* __restrict__ x,     // (4096,512)
    const float* __restrict__ W_in,  // (512,10)
    const float* __restrict__ b_in,  // (10)
    const float* __restrict__ W1,    // (10,64)
    const float* __restrict__ b1,    // (64)
    const float* __restrict__ W2,    // (64,256)
    const float* __restrict__ b2,    // (256)
    const uint2* __restrict__ terms, // (1024 padded)
    const float* __restrict__ Rmat,  // (10,8)
    float* __restrict__ out)         // (4096,256)
{
    __shared__ float ang[RPB][NQ];
    __shared__ float E1[RPB][NQ][4];     // per-site {1, <X>, <Z>, <Y>} (code=x|z<<1)
    __shared__ float E2d[RPB][5][32];    // pair products, duplicated x2
    __shared__ float part[RPB][256];
    __shared__ float zsh[RPB][NQ];
    __shared__ float hsh[RPB][64];

    const int t = threadIdx.x;
    const int lane = t & 63;
    const int wv = t >> 6;               // wave id = row within block
    const int row0 = blockIdx.x * RPB;

    // ---- p1: wave wv computes angles for row row0+wv ----
    {
        float acc[NQ];
        #pragma unroll
        for (int q = 0; q < NQ; ++q) acc[q] = 0.f;
        const float* xr = x + (size_t)(row0 + wv) * 512;
        for (int k = 0; k < 8; ++k) {
            int j = lane + 64 * k;
            float xv = xr[j];
            const float2* wr = (const float2*)(W_in + j * NQ);
            #pragma unroll
            for (int h = 0; h < 5; ++h) {
                float2 w2 = wr[h];
                acc[2 * h]     = fmaf(xv, w2.x, acc[2 * h]);
                acc[2 * h + 1] = fmaf(xv, w2.y, acc[2 * h + 1]);
            }
        }
        #pragma unroll
        for (int off = 32; off > 0; off >>= 1) {
            #pragma unroll
            for (int q = 0; q < NQ; ++q) acc[q] += __shfl_xor(acc[q], off);
        }
        if (lane == 0) {
            #pragma unroll
            for (int q = 0; q < NQ; ++q) ang[wv][q] = acc[q];
        }
    }
    __syncthreads();

    // ---- p2: per-(row,qubit) Bloch expectations of u = Rot0 * RX |0> ----
    if (t < RPB * NQ) {
        const int rr = t / NQ, i = t % NQ;
        float a = ang[rr][i] + b_in[i];
        float s, c; sincosf(0.5f * a, &s, &c);
        const float* Rp = Rmat + i * 8;
        float2 u0 = make_float2(fmaf(Rp[0], c, s * Rp[3]), fmaf(Rp[1], c, -s * Rp[2]));
        float2 u1 = make_float2(fmaf(Rp[4], c, s * Rp[7]), fmaf(Rp[5], c, -s * Rp[6]));
        float ex = 2.f * (u0.x * u1.x + u0.y * u1.y);
        float ey = 2.f * (u0.x * u1.y - u0.y * u1.x);
        float ez = u0.x * u0.x + u0.y * u0.y - u1.x * u1.x - u1.y * u1.y;
        E1[rr][i][0] = 1.f; E1[rr][i][1] = ex; E1[rr][i][2] = ez; E1[rr][i][3] = ey;
    }
    __syncthreads();

    // ---- pair products, duplicated for conflict-free reads ----
    if (t < 80) {
        const int rr = t / 20, rem = t % 20, p = rem / 4, c1 = rem % 4;
        const float e1 = E1[rr][2 * p + 1][c1];
        #pragma unroll
        for (int c0 = 0; c0 < 4; ++c0) {
            float v = E1[rr][2 * p][c0] * e1;
            int idx = c0 | (c1 << 2);
            E2d[rr][p][2 * idx]     = v;
            E2d[rr][p][2 * idx + 1] = v;
        }
    }
    __syncthreads();

    // ---- p3: contract terms (threads partitioned by output q, padded table) ----
    {
        int l, nqt, off;
        if      (t < 24)  { l = t;       nqt = 24; off = 0;   }
        else if (t < 48)  { l = t - 24;  nqt = 24; off = 96;  }
        else if (t < 51)  { l = t - 48;  nqt = 3;  off = 192; }
        else if (t < 54)  { l = t - 51;  nqt = 3;  off = 204; }
        else if (t < 62)  { l = t - 54;  nqt = 8;  off = 216; }
        else if (t < 70)  { l = t - 62;  nqt = 8;  off = 248; }
        else if (t < 94)  { l = t - 70;  nqt = 24; off = 280; }
        else if (t < 118) { l = t - 94;  nqt = 24; off = 376; }
        else if (t < 187) { l = t - 118; nqt = 69; off = 472; }
        else              { l = t - 187; nqt = 69; off = 748; }

        const int par = t & 1;
        float accR[RPB];
        #pragma unroll
        for (int rr = 0; rr < RPB; ++rr) accR[rr] = 0.f;

        for (int jj = 0; jj < 4; ++jj) {
            uint2 tm = terms[off + l + jj * nqt];   // always valid (padded)
            const float coef = __uint_as_float(tm.y);
            const unsigned nib = tm.x;
            #pragma unroll
            for (int rr = 0; rr < RPB; ++rr) {
                float pr = coef;
                #pragma unroll
                for (int p = 0; p < 5; ++p)
                    pr *= E2d[rr][p][2 * ((nib >> (4 * p)) & 15u) + par];
                accR[rr] += pr;
            }
        }
        #pragma unroll
        for (int rr = 0; rr < RPB; ++rr) part[rr][t] = accR[rr];
    }
    __syncthreads();

    // ---- group reduction: 40 threads, one per (row, q) ----
    if (t < RPB * NQ) {
        const int rr = t / NQ, q = t % NQ;
        int lo, hi;
        if      (q == 0) { lo = 0;   hi = 24;  }
        else if (q == 1) { lo = 24;  hi = 48;  }
        else if (q == 2) { lo = 48;  hi = 51;  }
        else if (q == 3) { lo = 51;  hi = 54;  }
        else if (q == 4) { lo = 54;  hi = 62;  }
        else if (q == 5) { lo = 62;  hi = 70;  }
        else if (q == 6) { lo = 70;  hi = 94;  }
        else if (q == 7) { lo = 94;  hi = 118; }
        else if (q == 8) { lo = 118; hi = 187; }
        else             { lo = 187; hi = 256; }
        float s = 0.f;
        for (int j = lo; j < hi; ++j) s += part[rr][j];
        zsh[rr][q] = s;
    }
    __syncthreads();

    // ---- p4: h = relu(z @ W1 + b1); 4 rows x 64 cols = 256 threads ----
    {
        const int rr = t >> 6, c = t & 63;
        float a = b1[c];
        #pragma unroll
        for (int i = 0; i < NQ; ++i) a = fmaf(zsh[rr][i], W1[i * 64 + c], a);
        hsh[rr][c] = fmaxf(a, 0.f);
    }
    __syncthreads();

    // ---- p5: out = tanh(h @ W2 + b2), thread owns column t for 4 rows ----
    {
        float oacc[RPB];
        #pragma unroll
        for (int rr = 0; rr < RPB; ++rr) oacc[rr] = b2[t];
        for (int j4 = 0; j4 < 16; ++j4) {
            float4 hv[RPB];
            #pragma unroll
            for (int rr = 0; rr < RPB; ++rr) hv[rr] = *(const float4*)&hsh[rr][4 * j4];
            const float w0 = W2[(4 * j4 + 0) * 256 + t];
            const float w1 = W2[(4 * j4 + 1) * 256 + t];
            const float w2 = W2[(4 * j4 + 2) * 256 + t];
            const float w3 = W2[(4 * j4 + 3) * 256 + t];
            #pragma unroll
            for (int rr = 0; rr < RPB; ++rr) {
                oacc[rr] = fmaf(hv[rr].x, w0, oacc[rr]);
                oacc[rr] = fmaf(hv[rr].y, w1, oacc[rr]);
                oacc[rr] = fmaf(hv[rr].z, w2, oacc[rr]);
                oacc[rr] = fmaf(hv[rr].w, w3, oacc[rr]);
            }
        }
        #pragma unroll
        for (int rr = 0; rr < RPB; ++rr)
            out[(size_t)(row0 + rr) * 256 + t] = tanhf(oacc[rr]);
    }
}

extern "C" void kernel_launch(void* const* d_in, const int* in_sizes, int n_in,
                              void* d_out, int out_size, void* d_ws, size_t ws_size,
                              hipStream_t stream) {
    const float* x    = (const float*)d_in[0];
    const float* W_in = (const float*)d_in[1];
    const float* b_in = (const float*)d_in[2];
    const float* qw   = (const float*)d_in[3];
    const float* W1   = (const float*)d_in[4];
    const float* b1   = (const float*)d_in[5];
    const float* W2   = (const float*)d_in[6];
    const float* b2   = (const float*)d_in[7];
    float* out = (float*)d_out;

    uint2* terms = (uint2*)d_ws;                       // 1024*8 = 8192 B
    float* Rmat  = (float*)((char*)d_ws + 8192);       // 80 floats

    qse_setup<<<1, 1024, 0, stream>>>(qw, terms, Rmat);
    qse_main<<<4096 / RPB, 256, 0, stream>>>(x, W_in, b_in, W1, b1, W2, b2,
                                             (const uint2*)terms, (const float*)Rmat, out);
}